// Round 1
// baseline (445.702 us; speedup 1.0000x reference)
//
#include <hip/hip_runtime.h>
#include <math.h>

#define D 256        // d_in == d_out == 256
#define TM 32        // target rows per block (1250 blocks: good tail balance)
#define KC 16        // K-chunk for W staging
#define LN_EPS 1e-5f
#define SCAN_CHUNK 1024   // elements per block in scan kernels

// ---------------------------------------------------------------------------
// CSR build: histogram -> exclusive scan (3 kernels) -> reorder
// ---------------------------------------------------------------------------
__global__ __launch_bounds__(256) void hist_kernel(
    const int* __restrict__ rows, int* __restrict__ cnt, int nnz)
{
    const int e = blockIdx.x * 256 + threadIdx.x;
    if (e < nnz) atomicAdd(&cnt[rows[e]], 1);
}

__global__ __launch_bounds__(256) void scan1_kernel(
    const int* __restrict__ cnt, int* __restrict__ row_ptr,
    int* __restrict__ partials, int n)
{
    const int tid = threadIdx.x;
    const int base = blockIdx.x * SCAN_CHUNK + tid * 4;
    int v[4];
#pragma unroll
    for (int q = 0; q < 4; q++) {
        const int i = base + q;
        v[q] = (i < n) ? cnt[i] : 0;
    }
    const int tsum = v[0] + v[1] + v[2] + v[3];

    const int lane = tid & 63;
    int s = tsum;
#pragma unroll
    for (int off = 1; off < 64; off <<= 1) {
        const int t = __shfl_up(s, off);
        if (lane >= off) s += t;
    }
    __shared__ int wtot[4];
    if (lane == 63) wtot[tid >> 6] = s;
    __syncthreads();
    const int w = tid >> 6;
    int woff = 0;
#pragma unroll
    for (int u = 0; u < 4; u++) if (u < w) woff += wtot[u];

    int run = woff + s - tsum;
#pragma unroll
    for (int q = 0; q < 4; q++) {
        const int i = base + q;
        if (i < n) row_ptr[i] = run;
        run += v[q];
    }
    if (tid == 255) partials[blockIdx.x] = woff + s;
}

__global__ __launch_bounds__(64) void scan2_kernel(int* __restrict__ partials, int nb)
{
    const int t = threadIdx.x;
    const int v = (t < nb) ? partials[t] : 0;
    int s = v;
#pragma unroll
    for (int off = 1; off < 64; off <<= 1) {
        const int u = __shfl_up(s, off);
        if (t >= off) s += u;
    }
    if (t < nb) partials[t] = s - v;
}

__global__ __launch_bounds__(256) void scan3_kernel(
    int* __restrict__ row_ptr, int* __restrict__ cursor,
    const int* __restrict__ partials, int n, int nnz)
{
    const int tid = threadIdx.x;
    const int base = blockIdx.x * SCAN_CHUNK + tid * 4;
    const int add = partials[blockIdx.x];
#pragma unroll
    for (int q = 0; q < 4; q++) {
        const int i = base + q;
        if (i < n) {
            const int rp = row_ptr[i] + add;
            row_ptr[i] = rp;
            cursor[i]  = rp;
        }
    }
    if (blockIdx.x == 0 && tid == 0) row_ptr[n] = nnz;
}

__global__ __launch_bounds__(256) void reorder_kernel(
    const int* __restrict__ rows, const int* __restrict__ cols,
    const float* __restrict__ vals, int* __restrict__ cursor,
    int* __restrict__ scol, float* __restrict__ sval, int nnz)
{
    const int e = blockIdx.x * 256 + threadIdx.x;
    if (e < nnz) {
        const int r = rows[e];
        const int pos = atomicAdd(&cursor[r], 1);
        scol[pos] = cols[e];
        sval[pos] = vals[e];
    }
}

// ---------------------------------------------------------------------------
// FUSED gather-SpMM + GEMM + bias + LayerNorm + GELU.
//
// Phase 1 (gather): wave w gathers rows r0+8w .. r0+8w+7 into LDS As[32][256].
//   - row_ptr for all 8 rows loaded lane-parallel once, broadcast via shfl.
//   - (col,val) pairs loaded lane-parallel (one edge per lane, <=64 per round)
//     and broadcast via shfl, so the index load is OFF the per-edge x-load
//     dependency chain. x-row loads stay unroll-4 (4 independent 1KB reads).
// Phase 2 (GEMM): the proven 32x256 tile, A read from resident As (broadcast
//   reads, conflict-free), W staged per-KC-chunk into Bs. acc[4][8]/thread.
// Epilogue: bias + LayerNorm + exact-erf GELU, float4 stores.
//
// LDS = 32KB (As) + 16KB (Bs) = 48KB -> 3 blocks/CU; co-resident blocks
// overlap gather (memory-bound) with GEMM (VALU-bound).
// NOTE: no min-waves launch_bounds arg — a forced cap makes acc[][] spill.
// n_tgt = 40000 = 1250*32 exactly -> no row guards.
// ---------------------------------------------------------------------------
__global__ __launch_bounds__(256) void fused_spmm_gemm_kernel(
    const float* __restrict__ x, const int* __restrict__ row_ptr,
    const int* __restrict__ scol, const float* __restrict__ sval,
    const float* __restrict__ Wm, const float* __restrict__ bias,
    const float* __restrict__ gamma, const float* __restrict__ beta,
    float* __restrict__ out)
{
    __shared__ float As[TM][D];        // 32 KB: gathered rows (fp32)
    __shared__ float Bs[KC][D];        // 16 KB: W K-chunk

    const int tid  = threadIdx.x;
    const int wv   = tid >> 6;         // wave 0..3
    const int lane = tid & 63;
    const int r0   = blockIdx.x * TM;

    // ---- Phase 1: gather 8 rows per wave ----
    const int rbase = r0 + wv * 8;
    int rp = 0;
    if (lane < 9) rp = row_ptr[rbase + lane];   // rbase+8 <= n_tgt, valid

    for (int rr = 0; rr < 8; rr++) {
        const int beg = __shfl(rp, rr);
        const int end = __shfl(rp, rr + 1);

        float4 a0 = make_float4(0.f, 0.f, 0.f, 0.f);
        float4 a1 = a0, a2 = a0, a3 = a0;

        for (int cb = beg; cb < end; cb += 64) {
            const int cnt = min(64, end - cb);
            int   cidx = 0;
            float cval = 0.f;
            if (lane < cnt) {
                cidx = scol[cb + lane];
                cval = sval[cb + lane];
            }
            int j = 0;
            for (; j + 4 <= cnt; j += 4) {
                const int   c0 = __shfl(cidx, j);
                const int   c1 = __shfl(cidx, j + 1);
                const int   c2 = __shfl(cidx, j + 2);
                const int   c3 = __shfl(cidx, j + 3);
                const float v0 = __shfl(cval, j);
                const float v1 = __shfl(cval, j + 1);
                const float v2 = __shfl(cval, j + 2);
                const float v3 = __shfl(cval, j + 3);
                const float4 x0 = *(const float4*)(x + (size_t)c0 * D + 4 * lane);
                const float4 x1 = *(const float4*)(x + (size_t)c1 * D + 4 * lane);
                const float4 x2 = *(const float4*)(x + (size_t)c2 * D + 4 * lane);
                const float4 x3 = *(const float4*)(x + (size_t)c3 * D + 4 * lane);
                a0.x = fmaf(v0, x0.x, a0.x); a0.y = fmaf(v0, x0.y, a0.y);
                a0.z = fmaf(v0, x0.z, a0.z); a0.w = fmaf(v0, x0.w, a0.w);
                a1.x = fmaf(v1, x1.x, a1.x); a1.y = fmaf(v1, x1.y, a1.y);
                a1.z = fmaf(v1, x1.z, a1.z); a1.w = fmaf(v1, x1.w, a1.w);
                a2.x = fmaf(v2, x2.x, a2.x); a2.y = fmaf(v2, x2.y, a2.y);
                a2.z = fmaf(v2, x2.z, a2.z); a2.w = fmaf(v2, x2.w, a2.w);
                a3.x = fmaf(v3, x3.x, a3.x); a3.y = fmaf(v3, x3.y, a3.y);
                a3.z = fmaf(v3, x3.z, a3.z); a3.w = fmaf(v3, x3.w, a3.w);
            }
            for (; j < cnt; j++) {
                const int   c0 = __shfl(cidx, j);
                const float v0 = __shfl(cval, j);
                const float4 x0 = *(const float4*)(x + (size_t)c0 * D + 4 * lane);
                a0.x = fmaf(v0, x0.x, a0.x); a0.y = fmaf(v0, x0.y, a0.y);
                a0.z = fmaf(v0, x0.z, a0.z); a0.w = fmaf(v0, x0.w, a0.w);
            }
        }
        const float4 s = make_float4(a0.x + a1.x + a2.x + a3.x,
                                     a0.y + a1.y + a2.y + a3.y,
                                     a0.z + a1.z + a2.z + a3.z,
                                     a0.w + a1.w + a2.w + a3.w);
        *(float4*)&As[wv * 8 + rr][4 * lane] = s;
    }
    __syncthreads();

    // ---- Phase 2: GEMM from resident As ----
    const int tr = tid >> 5;   // 0..7
    const int tc = tid & 31;   // 0..31

    float acc[4][8];
#pragma unroll
    for (int i = 0; i < 4; i++)
#pragma unroll
        for (int j = 0; j < 8; j++) acc[i][j] = 0.f;

    for (int k0 = 0; k0 < D; k0 += KC) {
        // stage B: 16 x 256 = 1024 float4 slots, 4 per thread
#pragma unroll
        for (int q = 0; q < 4; q++) {
            const int idx = q * 256 + tid;
            const int kk = idx >> 6;
            const int c4 = (idx & 63) * 4;
            *(float4*)&Bs[kk][c4] = *(const float4*)(Wm + (size_t)(k0 + kk) * D + c4);
        }
        __syncthreads();

#pragma unroll
        for (int q = 0; q < 4; q++) {        // k-quads within chunk
            float4 a4[4];
#pragma unroll
            for (int i = 0; i < 4; i++)
                a4[i] = *(const float4*)&As[tr * 4 + i][k0 + q * 4];
#pragma unroll
            for (int kk = 0; kk < 4; kk++) {
                const float4 b0 = *(const float4*)&Bs[q * 4 + kk][4 * tc];
                const float4 b1 = *(const float4*)&Bs[q * 4 + kk][128 + 4 * tc];
#pragma unroll
                for (int i = 0; i < 4; i++) {
                    const float ai = (kk == 0) ? a4[i].x :
                                     (kk == 1) ? a4[i].y :
                                     (kk == 2) ? a4[i].z : a4[i].w;
                    acc[i][0] = fmaf(ai, b0.x, acc[i][0]);
                    acc[i][1] = fmaf(ai, b0.y, acc[i][1]);
                    acc[i][2] = fmaf(ai, b0.z, acc[i][2]);
                    acc[i][3] = fmaf(ai, b0.w, acc[i][3]);
                    acc[i][4] = fmaf(ai, b1.x, acc[i][4]);
                    acc[i][5] = fmaf(ai, b1.y, acc[i][5]);
                    acc[i][6] = fmaf(ai, b1.z, acc[i][6]);
                    acc[i][7] = fmaf(ai, b1.w, acc[i][7]);
                }
            }
        }
        __syncthreads();
    }

    // ---- epilogue: bias + LayerNorm + exact GELU
    float gm[8], bt[8], bs[8];
#pragma unroll
    for (int j = 0; j < 8; j++) {
        const int c = (j < 4) ? (4 * tc + j) : (128 + 4 * tc + (j - 4));
        gm[j] = gamma[c]; bt[j] = beta[c]; bs[j] = bias[c];
    }

#pragma unroll
    for (int i = 0; i < 4; i++) {
        float s = 0.f, ss = 0.f;
#pragma unroll
        for (int j = 0; j < 8; j++) {
            const float h = acc[i][j] + bs[j];
            acc[i][j] = h;
            s += h; ss += h * h;
        }
#pragma unroll
        for (int off = 16; off > 0; off >>= 1) {
            s  += __shfl_xor(s,  off);
            ss += __shfl_xor(ss, off);
        }
        const float mean = s * (1.f / D);
        const float var  = ss * (1.f / D) - mean * mean;
        const float rstd = rsqrtf(var + LN_EPS);

        const int row = r0 + tr * 4 + i;
        float y[8];
#pragma unroll
        for (int j = 0; j < 8; j++) {
            const float v = (acc[i][j] - mean) * rstd * gm[j] + bt[j];
            y[j] = 0.5f * v * (1.f + erff(v * 0.70710678118654752f));
        }
        float* op = out + (size_t)row * D;
        *(float4*)(op + 4 * tc)       = make_float4(y[0], y[1], y[2], y[3]);
        *(float4*)(op + 128 + 4 * tc) = make_float4(y[4], y[5], y[6], y[7]);
    }
}

// ---------------------------------------------------------------------------
extern "C" void kernel_launch(void* const* d_in, const int* in_sizes, int n_in,
                              void* d_out, int out_size, void* d_ws, size_t ws_size,
                              hipStream_t stream) {
    const float* x     = (const float*)d_in[0];
    const int*   rows  = (const int*)d_in[1];
    const int*   cols  = (const int*)d_in[2];
    const float* vals  = (const float*)d_in[3];
    const float* Wm    = (const float*)d_in[4];
    const float* bias  = (const float*)d_in[5];
    const float* gamma = (const float*)d_in[6];
    const float* beta  = (const float*)d_in[7];
    float* out = (float*)d_out;

    const int nnz   = in_sizes[1];
    const int n_tgt = out_size / D;          // 40000

    // workspace layout (mapped buffer eliminated by fusion)
    int* cnt      = (int*)d_ws;                         // [n_tgt]
    int* row_ptr  = cnt + n_tgt;                        // [n_tgt+1]
    int* cursor   = row_ptr + n_tgt + 1;                // [n_tgt]
    int* partials = cursor + n_tgt;                     // [64]
    int* scol     = partials + 64;                      // [nnz]
    float* sval   = (float*)(scol + nnz);               // [nnz]

    hipMemsetAsync(cnt, 0, (size_t)n_tgt * sizeof(int), stream);

    const int eblocks = (nnz + 255) / 256;
    hist_kernel<<<eblocks, 256, 0, stream>>>(rows, cnt, nnz);

    const int sblocks = (n_tgt + SCAN_CHUNK - 1) / SCAN_CHUNK;   // 40
    scan1_kernel<<<sblocks, 256, 0, stream>>>(cnt, row_ptr, partials, n_tgt);
    scan2_kernel<<<1, 64, 0, stream>>>(partials, sblocks);
    scan3_kernel<<<sblocks, 256, 0, stream>>>(row_ptr, cursor, partials, n_tgt, nnz);

    reorder_kernel<<<eblocks, 256, 0, stream>>>(rows, cols, vals, cursor,
                                                scol, sval, nnz);

    const int gblocks = n_tgt / TM;   // 1250
    fused_spmm_gemm_kernel<<<gblocks, 256, 0, stream>>>(
        x, row_ptr, scol, sval, Wm, bias, gamma, beta, out);
}

// Round 2
// 424.169 us; speedup vs baseline: 1.0508x; 1.0508x over previous
//
#include <hip/hip_runtime.h>
#include <math.h>

#define D 256        // d_in == d_out == 256
#define TM 32        // target rows per block (1250 blocks)
#define KC 8         // K-chunk for W staging (8KB Bs -> 40KB LDS -> 4 blocks/CU)
#define LN_EPS 1e-5f
#define SCAN_CHUNK 1024   // elements per block in scan kernels

// ---------------------------------------------------------------------------
// CSR build: histogram -> scan (2 kernels) -> reorder
// ---------------------------------------------------------------------------
__global__ __launch_bounds__(256) void hist_kernel(
    const int* __restrict__ rows, int* __restrict__ cnt, int nnz)
{
    const int e = blockIdx.x * 256 + threadIdx.x;
    if (e < nnz) atomicAdd(&cnt[rows[e]], 1);
}

__global__ __launch_bounds__(256) void scan1_kernel(
    const int* __restrict__ cnt, int* __restrict__ row_ptr,
    int* __restrict__ partials, int n)
{
    const int tid = threadIdx.x;
    const int base = blockIdx.x * SCAN_CHUNK + tid * 4;
    int v[4];
#pragma unroll
    for (int q = 0; q < 4; q++) {
        const int i = base + q;
        v[q] = (i < n) ? cnt[i] : 0;
    }
    const int tsum = v[0] + v[1] + v[2] + v[3];

    const int lane = tid & 63;
    int s = tsum;
#pragma unroll
    for (int off = 1; off < 64; off <<= 1) {
        const int t = __shfl_up(s, off);
        if (lane >= off) s += t;
    }
    __shared__ int wtot[4];
    if (lane == 63) wtot[tid >> 6] = s;
    __syncthreads();
    const int w = tid >> 6;
    int woff = 0;
#pragma unroll
    for (int u = 0; u < 4; u++) if (u < w) woff += wtot[u];

    int run = woff + s - tsum;
#pragma unroll
    for (int q = 0; q < 4; q++) {
        const int i = base + q;
        if (i < n) row_ptr[i] = run;
        run += v[q];
    }
    if (tid == 255) partials[blockIdx.x] = woff + s;
}

// Merged scan2+scan3: each block wave-scans the (<=64) partials itself
// (redundant but trivial), then applies its exclusive prefix. One launch
// fewer on the serial CSR dependency chain.
__global__ __launch_bounds__(256) void scan23_kernel(
    int* __restrict__ row_ptr, int* __restrict__ cursor,
    const int* __restrict__ partials, int n, int nnz, int nb)
{
    const int tid = threadIdx.x;
    __shared__ int s_add;
    if (tid < 64) {
        const int v = (tid < nb) ? partials[tid] : 0;
        int s = v;
#pragma unroll
        for (int off = 1; off < 64; off <<= 1) {
            const int u = __shfl_up(s, off);
            if (tid >= off) s += u;
        }
        if (tid == (int)blockIdx.x) s_add = s - v;   // exclusive prefix
    }
    __syncthreads();
    const int add = s_add;

    const int base = blockIdx.x * SCAN_CHUNK + tid * 4;
#pragma unroll
    for (int q = 0; q < 4; q++) {
        const int i = base + q;
        if (i < n) {
            const int rp = row_ptr[i] + add;
            row_ptr[i] = rp;
            cursor[i]  = rp;
        }
    }
    if (blockIdx.x == 0 && tid == 0) row_ptr[n] = nnz;
}

__global__ __launch_bounds__(256) void reorder_kernel(
    const int* __restrict__ rows, const int* __restrict__ cols,
    const float* __restrict__ vals, int* __restrict__ cursor,
    int* __restrict__ scol, float* __restrict__ sval, int nnz)
{
    const int e = blockIdx.x * 256 + threadIdx.x;
    if (e < nnz) {
        const int r = rows[e];
        const int pos = atomicAdd(&cursor[r], 1);
        scol[pos] = cols[e];
        sval[pos] = vals[e];
    }
}

// ---------------------------------------------------------------------------
// FUSED gather-SpMM + GEMM + bias + LayerNorm + GELU.
//
// Round-1 post-mortem: latency-bound (12% HBM, 29% VALU, 27% occ). Avg row
// length is 7, so the old unroll-4 loop left a 3-deep SERIAL remainder chain
// of ~600cy loads per row. Fixes this round:
//   - 8-wide batched edge loads with masked tail: per row issue min(cnt,8)
//     INDEPENDENT x-row loads back-to-back (pad lanes re-load edge 0 with
//     weight 0 -> L1 hit, numerically a no-op). No serial remainder.
//   - KC 16->8: LDS 48KB -> 40KB -> 4 blocks/CU (16 waves/CU, +33% TLP).
// Phase 2 (GEMM) unchanged 32x256 tile, acc[4][8]/thread; LDS bank-conflict
// counter was 0, so no padding/swizzle needed.
// NOTE: no min-waves launch_bounds arg — a forced cap makes acc[][] spill.
// n_tgt = 40000 = 1250*32 exactly -> no row guards.
// ---------------------------------------------------------------------------
__global__ __launch_bounds__(256) void fused_spmm_gemm_kernel(
    const float* __restrict__ x, const int* __restrict__ row_ptr,
    const int* __restrict__ scol, const float* __restrict__ sval,
    const float* __restrict__ Wm, const float* __restrict__ bias,
    const float* __restrict__ gamma, const float* __restrict__ beta,
    float* __restrict__ out)
{
    __shared__ float As[TM][D];        // 32 KB: gathered rows (fp32)
    __shared__ float Bs[KC][D];        // 8 KB: W K-chunk

    const int tid  = threadIdx.x;
    const int wv   = tid >> 6;         // wave 0..3
    const int lane = tid & 63;
    const int r0   = blockIdx.x * TM;

    // ---- Phase 1: gather 8 rows per wave ----
    const int rbase = r0 + wv * 8;
    int rp = 0;
    if (lane < 9) rp = row_ptr[rbase + lane];   // rbase+8 <= n_tgt, valid

    for (int rr = 0; rr < 8; rr++) {
        const int beg = __shfl(rp, rr);
        const int end = __shfl(rp, rr + 1);

        float4 a0 = make_float4(0.f, 0.f, 0.f, 0.f);
        float4 a1 = a0, a2 = a0, a3 = a0;

        for (int cb = beg; cb < end; cb += 64) {
            const int cnt = min(64, end - cb);
            int   cidx = 0;
            float cval = 0.f;
            if (lane < cnt) {
                cidx = scol[cb + lane];
                cval = sval[cb + lane];
            }
            for (int j = 0; j < cnt; j += 8) {
                // broadcast 8 (col, val) pairs; pad slots use edge j+0 with v=0
                int   cc[8];
                float vv[8];
#pragma unroll
                for (int u = 0; u < 8; u++) {
                    const int idx = j + u;
                    const int sl  = (idx < cnt) ? idx : j;   // uniform
                    cc[u] = __shfl(cidx, sl);
                    vv[u] = (idx < cnt) ? __shfl(cval, sl) : 0.f;
                }
                // issue all 8 independent 1KB row loads before any FMA
                float4 xv[8];
#pragma unroll
                for (int u = 0; u < 8; u++)
                    xv[u] = *(const float4*)(x + (size_t)cc[u] * D + 4 * lane);
#pragma unroll
                for (int u = 0; u < 8; u++) {
                    float4& a = (u & 3) == 0 ? a0 : (u & 3) == 1 ? a1 :
                                (u & 3) == 2 ? a2 : a3;
                    a.x = fmaf(vv[u], xv[u].x, a.x);
                    a.y = fmaf(vv[u], xv[u].y, a.y);
                    a.z = fmaf(vv[u], xv[u].z, a.z);
                    a.w = fmaf(vv[u], xv[u].w, a.w);
                }
            }
        }
        const float4 s = make_float4(a0.x + a1.x + a2.x + a3.x,
                                     a0.y + a1.y + a2.y + a3.y,
                                     a0.z + a1.z + a2.z + a3.z,
                                     a0.w + a1.w + a2.w + a3.w);
        *(float4*)&As[wv * 8 + rr][4 * lane] = s;
    }
    __syncthreads();

    // ---- Phase 2: GEMM from resident As ----
    const int tr = tid >> 5;   // 0..7
    const int tc = tid & 31;   // 0..31

    float acc[4][8];
#pragma unroll
    for (int i = 0; i < 4; i++)
#pragma unroll
        for (int j = 0; j < 8; j++) acc[i][j] = 0.f;

    for (int k0 = 0; k0 < D; k0 += KC) {
        // stage B: 8 x 256 = 512 float4 slots, 2 per thread
#pragma unroll
        for (int q = 0; q < 2; q++) {
            const int idx = q * 256 + tid;
            const int kk = idx >> 6;          // 0..7
            const int c4 = (idx & 63) * 4;
            *(float4*)&Bs[kk][c4] = *(const float4*)(Wm + (size_t)(k0 + kk) * D + c4);
        }
        __syncthreads();

#pragma unroll
        for (int q = 0; q < 2; q++) {        // k-quads within chunk
            float4 a4[4];
#pragma unroll
            for (int i = 0; i < 4; i++)
                a4[i] = *(const float4*)&As[tr * 4 + i][k0 + q * 4];
#pragma unroll
            for (int kk = 0; kk < 4; kk++) {
                const float4 b0 = *(const float4*)&Bs[q * 4 + kk][4 * tc];
                const float4 b1 = *(const float4*)&Bs[q * 4 + kk][128 + 4 * tc];
#pragma unroll
                for (int i = 0; i < 4; i++) {
                    const float ai = (kk == 0) ? a4[i].x :
                                     (kk == 1) ? a4[i].y :
                                     (kk == 2) ? a4[i].z : a4[i].w;
                    acc[i][0] = fmaf(ai, b0.x, acc[i][0]);
                    acc[i][1] = fmaf(ai, b0.y, acc[i][1]);
                    acc[i][2] = fmaf(ai, b0.z, acc[i][2]);
                    acc[i][3] = fmaf(ai, b0.w, acc[i][3]);
                    acc[i][4] = fmaf(ai, b1.x, acc[i][4]);
                    acc[i][5] = fmaf(ai, b1.y, acc[i][5]);
                    acc[i][6] = fmaf(ai, b1.z, acc[i][6]);
                    acc[i][7] = fmaf(ai, b1.w, acc[i][7]);
                }
            }
        }
        __syncthreads();
    }

    // ---- epilogue: bias + LayerNorm + exact GELU
    float gm[8], bt[8], bs[8];
#pragma unroll
    for (int j = 0; j < 8; j++) {
        const int c = (j < 4) ? (4 * tc + j) : (128 + 4 * tc + (j - 4));
        gm[j] = gamma[c]; bt[j] = beta[c]; bs[j] = bias[c];
    }

#pragma unroll
    for (int i = 0; i < 4; i++) {
        float s = 0.f, ss = 0.f;
#pragma unroll
        for (int j = 0; j < 8; j++) {
            const float h = acc[i][j] + bs[j];
            acc[i][j] = h;
            s += h; ss += h * h;
        }
#pragma unroll
        for (int off = 16; off > 0; off >>= 1) {
            s  += __shfl_xor(s,  off);
            ss += __shfl_xor(ss, off);
        }
        const float mean = s * (1.f / D);
        const float var  = ss * (1.f / D) - mean * mean;
        const float rstd = rsqrtf(var + LN_EPS);

        const int row = r0 + tr * 4 + i;
        float y[8];
#pragma unroll
        for (int j = 0; j < 8; j++) {
            const float v = (acc[i][j] - mean) * rstd * gm[j] + bt[j];
            y[j] = 0.5f * v * (1.f + erff(v * 0.70710678118654752f));
        }
        float* op = out + (size_t)row * D;
        *(float4*)(op + 4 * tc)       = make_float4(y[0], y[1], y[2], y[3]);
        *(float4*)(op + 128 + 4 * tc) = make_float4(y[4], y[5], y[6], y[7]);
    }
}

// ---------------------------------------------------------------------------
extern "C" void kernel_launch(void* const* d_in, const int* in_sizes, int n_in,
                              void* d_out, int out_size, void* d_ws, size_t ws_size,
                              hipStream_t stream) {
    const float* x     = (const float*)d_in[0];
    const int*   rows  = (const int*)d_in[1];
    const int*   cols  = (const int*)d_in[2];
    const float* vals  = (const float*)d_in[3];
    const float* Wm    = (const float*)d_in[4];
    const float* bias  = (const float*)d_in[5];
    const float* gamma = (const float*)d_in[6];
    const float* beta  = (const float*)d_in[7];
    float* out = (float*)d_out;

    const int nnz   = in_sizes[1];
    const int n_tgt = out_size / D;          // 40000

    // workspace layout
    int* cnt      = (int*)d_ws;                         // [n_tgt]
    int* row_ptr  = cnt + n_tgt;                        // [n_tgt+1]
    int* cursor   = row_ptr + n_tgt + 1;                // [n_tgt]
    int* partials = cursor + n_tgt;                     // [64]
    int* scol     = partials + 64;                      // [nnz]
    float* sval   = (float*)(scol + nnz);               // [nnz]

    hipMemsetAsync(cnt, 0, (size_t)n_tgt * sizeof(int), stream);

    const int eblocks = (nnz + 255) / 256;
    hist_kernel<<<eblocks, 256, 0, stream>>>(rows, cnt, nnz);

    const int sblocks = (n_tgt + SCAN_CHUNK - 1) / SCAN_CHUNK;   // 40
    scan1_kernel<<<sblocks, 256, 0, stream>>>(cnt, row_ptr, partials, n_tgt);
    scan23_kernel<<<sblocks, 256, 0, stream>>>(row_ptr, cursor, partials,
                                               n_tgt, nnz, sblocks);

    reorder_kernel<<<eblocks, 256, 0, stream>>>(rows, cols, vals, cursor,
                                                scol, sval, nnz);

    const int gblocks = n_tgt / TM;   // 1250
    fused_spmm_gemm_kernel<<<gblocks, 256, 0, stream>>>(
        x, row_ptr, scol, sval, Wm, bias, gamma, beta, out);
}